// Round 5
// baseline (319.100 us; speedup 1.0000x reference)
//
#include <hip/hip_runtime.h>
#include <hip/hip_bf16.h>
#include <math.h>

// attention scale folded with log2(e) for exp2-based softmax:
// q_attn = q * (256^-0.5 * log2(e))
#define QSC 0.09016844f

typedef __attribute__((ext_vector_type(8))) short bf16x8;
typedef __attribute__((ext_vector_type(4))) float f32x4;

// fp32 -> bf16 round-to-nearest-even
__device__ __forceinline__ ushort f2bf(float f) {
    unsigned u = __float_as_uint(f);
    return (ushort)((u + 0x7FFFu + ((u >> 16) & 1u)) >> 16);
}

__device__ __forceinline__ unsigned pk2bf(float a, float b) {
    __hip_bfloat162 h = __float22bfloat162_rn(make_float2(a, b));
    return *(unsigned*)&h;
}

// async global->LDS, 16B per lane. LDS dest must be wave-uniform base + lane*16.
__device__ __forceinline__ void gl_lds16(const ushort* g, ushort* l) {
    __builtin_amdgcn_global_load_lds(
        (const __attribute__((address_space(1))) unsigned int*)g,
        (__attribute__((address_space(3))) unsigned int*)l, 16, 0, 0);
}

// XOR swizzle for DMA-staged [row][4x8ushort] tiles: kills the 8-way
// fragment-read conflict (row stride 64B) without padding.
__device__ __forceinline__ int swz(int row) { return (row ^ (row >> 2)) & 3; }

// ---------------------------------------------------------------------------
// K0: weights -> transposed bf16
// ---------------------------------------------------------------------------
__global__ __launch_bounds__(256) void k_cast_w(const float* __restrict__ Wqkv,
                                                const float* __restrict__ Wo,
                                                ushort* __restrict__ Wqkvt,
                                                ushort* __restrict__ Wot) {
    int b = blockIdx.x, tid = threadIdx.x;
    if (b < 768) Wqkvt[b * 256 + tid] = f2bf(Wqkv[(size_t)tid * 768 + b]);
    else { int n = b - 768; Wot[n * 256 + tid] = f2bf(Wo[(size_t)tid * 256 + n]); }
}

// ---------------------------------------------------------------------------
// K1: fused window-gather cast (x -> xg bf16, window order) + window means
// (fp32, for the routing path). One pass over x.
// ---------------------------------------------------------------------------
__global__ __launch_bounds__(256) void k_prep(const float* __restrict__ x,
                                              ushort* __restrict__ xg,
                                              float* __restrict__ xmean) {
    int b = blockIdx.x;               // nd*49 + p
    int nd = b / 49, p = b % 49;
    int j = p / 7, i = p % 7;
    const float* xb = x + ((size_t)nd * 3136 + (j * 8) * 56 + i * 8) * 256 + threadIdx.x;
    ushort* xo = xg + (size_t)b * 64 * 256 + threadIdx.x;
    float s = 0.f;
#pragma unroll 2
    for (int hh = 0; hh < 8; ++hh)
#pragma unroll
        for (int ww = 0; ww < 8; ++ww) {
            float v = xb[(size_t)(hh * 56 + ww) * 256];
            s += v;
            xo[(size_t)(hh * 8 + ww) * 256] = f2bf(v);
        }
    xmean[(size_t)b * 256 + threadIdx.x] = s * (1.f / 64.f);
}

// ---------------------------------------------------------------------------
// Routing projection, pure fp32 (decoupled from bf16 numerics).
// ---------------------------------------------------------------------------
__global__ __launch_bounds__(256) void k_winproj(const float* __restrict__ xmean,
                                                 const float* __restrict__ Wqkv,
                                                 const float* __restrict__ bqkv,
                                                 float* __restrict__ qwin,
                                                 float* __restrict__ kwin) {
    __shared__ float As[16 * 68];
    __shared__ float Bs[16 * 64];
    const int tid = threadIdx.x;
    const int m0 = blockIdx.y * 64;
    const int n0 = blockIdx.x * 64;

    const int ar = tid >> 2;
    const int ak = (tid & 3) * 4;
    const int arow = (m0 + ar < 784) ? (m0 + ar) : 783;
    const float* aptr = xmean + (size_t)arow * 256 + ak;

    const int bk = tid >> 4;
    const int bn = (tid & 15) * 4;
    const float* bptr = Wqkv + (size_t)bk * 768 + n0 + bn;

    const int ty = tid >> 4, tx = tid & 15;
    float acc[4][4] = {};

    for (int kt = 0; kt < 256; kt += 16) {
        float4 av = *(const float4*)(aptr + kt);
        float4 bv = *(const float4*)(bptr + (size_t)kt * 768);
        __syncthreads();
        As[(ak + 0) * 68 + ar] = av.x;
        As[(ak + 1) * 68 + ar] = av.y;
        As[(ak + 2) * 68 + ar] = av.z;
        As[(ak + 3) * 68 + ar] = av.w;
        *(float4*)&Bs[bk * 64 + bn] = bv;
        __syncthreads();
#pragma unroll
        for (int kk = 0; kk < 16; ++kk) {
            float4 a4 = *(const float4*)&As[kk * 68 + ty * 4];
            float4 b4 = *(const float4*)&Bs[kk * 64 + tx * 4];
            float a[4] = {a4.x, a4.y, a4.z, a4.w};
            float b[4] = {b4.x, b4.y, b4.z, b4.w};
#pragma unroll
            for (int ii = 0; ii < 4; ++ii)
#pragma unroll
                for (int jj = 0; jj < 4; ++jj) acc[ii][jj] += a[ii] * b[jj];
        }
    }
#pragma unroll
    for (int ii = 0; ii < 4; ++ii) {
        int t = m0 + ty * 4 + ii;
        if (t >= 784) continue;
#pragma unroll
        for (int jj = 0; jj < 4; ++jj) {
            int col = n0 + tx * 4 + jj;
            float v = acc[ii][jj] + bqkv[col];
            if (col < 256) qwin[(size_t)t * 256 + col] = v;
            else           kwin[(size_t)t * 256 + (col - 256)] = v;
        }
    }
}

__global__ __launch_bounds__(64) void k_route(const float* __restrict__ qwin,
                                              const float* __restrict__ kwin,
                                              int* __restrict__ ridx) {
    const int b = blockIdx.x;                 // nd*49 + p
    const int nd = b / 49;
    const int ndkv = ((nd & 7) == 7) ? nd : nd + 1;
    const int t = threadIdx.x;
    __shared__ float qs[256];
    for (int i = t; i < 256; i += 64) qs[i] = qwin[b * 256 + i];
    __syncthreads();
    float logit = -INFINITY;
    if (t < 49) {
        const float* kr = kwin + ((size_t)ndkv * 49 + t) * 256;
        float s = 0.f;
        for (int c = 0; c < 256; ++c) s += qs[c] * kr[c];
        logit = s;
    }
    for (int sel = 0; sel < 4; ++sel) {
        float v = logit;
        int ix = t;
        for (int off = 32; off > 0; off >>= 1) {
            float ov = __shfl_xor(v, off);
            int   oi = __shfl_xor(ix, off);
            if (ov > v || (ov == v && oi < ix)) { v = ov; ix = oi; }
        }
        if (t == 0) ridx[b * 4 + sel] = ix;
        if (t == ix) logit = -INFINITY;
    }
}

// ---------------------------------------------------------------------------
// K2: bf16 MFMA GEMM, 128x128 tile, BK=32, direct-to-LDS staging with XOR
// swizzle (fragment reads 2-way bank aliased = free). q gets folded scale.
// ---------------------------------------------------------------------------
__global__ __launch_bounds__(256) void k_gemm_qkv(const ushort* __restrict__ A,
                                                  const ushort* __restrict__ Bt,
                                                  const float* __restrict__ bqkv,
                                                  ushort* __restrict__ q,
                                                  ushort* __restrict__ kv) {
    __shared__ ushort As[128 * 32];
    __shared__ ushort Bs[128 * 32];
    const int tid = threadIdx.x;
    const int wv = tid >> 6, ln = tid & 63;
    const int lane15 = ln & 15, quad = ln >> 4;
    const int m0 = blockIdx.y * 128, n0 = blockIdx.x * 128;
    const int row0 = tid >> 2, ck0 = tid & 3;

    const ushort* gA[2]; const ushort* gB[2];
    ushort* lA[2]; ushort* lB[2];
#pragma unroll
    for (int p = 0; p < 2; ++p) {
        int r = p * 64 + row0;
        int cks = ck0 ^ swz(r);               // swizzled chunk this lane stages
        gA[p] = A  + (size_t)(m0 + r) * 256 + cks * 8;
        gB[p] = Bt + (size_t)(n0 + r) * 256 + cks * 8;
        lA[p] = &As[(p * 256 + tid) * 8];
        lB[p] = &Bs[(p * 256 + tid) * 8];
    }

    f32x4 acc[4][4];
#pragma unroll
    for (int i = 0; i < 4; ++i)
#pragma unroll
        for (int j = 0; j < 4; ++j) acc[i][j] = (f32x4){0.f, 0.f, 0.f, 0.f};

    const int mb = (wv >> 1) * 64, nb = (wv & 1) * 64;

    for (int kt = 0; kt < 8; ++kt) {
        __syncthreads();
#pragma unroll
        for (int p = 0; p < 2; ++p) {
            gl_lds16(gA[p] + kt * 32, lA[p]);
            gl_lds16(gB[p] + kt * 32, lB[p]);
        }
        __syncthreads();
        bf16x8 aF[4], bF[4];
#pragma unroll
        for (int mt = 0; mt < 4; ++mt) {
            int r = mb + mt * 16 + lane15;
            aF[mt] = *(const bf16x8*)&As[r * 32 + (quad ^ swz(r)) * 8];
        }
#pragma unroll
        for (int nt = 0; nt < 4; ++nt) {
            int r = nb + nt * 16 + lane15;
            bF[nt] = *(const bf16x8*)&Bs[r * 32 + (quad ^ swz(r)) * 8];
        }
#pragma unroll
        for (int mt = 0; mt < 4; ++mt)
#pragma unroll
            for (int nt = 0; nt < 4; ++nt)
                acc[mt][nt] = __builtin_amdgcn_mfma_f32_16x16x32_bf16(aF[mt], bF[nt], acc[mt][nt], 0, 0, 0);
    }

#pragma unroll
    for (int mt = 0; mt < 4; ++mt) {
#pragma unroll
        for (int nt = 0; nt < 4; ++nt) {
            int col = n0 + nb + nt * 16 + lane15;
            float bias = bqkv[col];
#pragma unroll
            for (int r = 0; r < 4; ++r) {
                int t = m0 + mb + mt * 16 + quad * 4 + r;
                float v = acc[mt][nt][r] + bias;
                if (col < 256) q[(size_t)t * 256 + col] = f2bf(v * QSC);
                else           kv[(size_t)t * 512 + (col - 256)] = f2bf(v);
            }
        }
    }
}

// ---------------------------------------------------------------------------
// K3: fused attention (8 heads looped) + output projection + scatter.
// One block per (window p, nd). q carries SCALE*log2e: softmax = exp2(score),
// normalization applied at the Obuf write. O @ Wo with B-frags from L2.
// LDS: Ks 20K + Vt 16.9K + Ps 9.2K + Obuf 33.8K = 80.4 KB -> 2 blocks/CU.
// ---------------------------------------------------------------------------
__global__ __launch_bounds__(256) void k_attn_o(const ushort* __restrict__ qbuf,
                                                const ushort* __restrict__ kvbuf,
                                                const ushort* __restrict__ Wot,
                                                const int* __restrict__ ridx,
                                                const float* __restrict__ bo,
                                                float* __restrict__ out) {
    const int p = blockIdx.x, nd = blockIdx.y;
    const int ndkv = ((nd & 7) == 7) ? nd : nd + 1;
    const int tid = threadIdx.x;
    const int wv = tid >> 6, ln = tid & 63;
    const int lane15 = ln & 15, quad = ln >> 4;

    __shared__ ushort Ks[256 * 40];    // [key][ch]  per-head
    __shared__ ushort Vt[32 * 264];    // [ch][key]  per-head
    __shared__ ushort Ps[64 * 72];     // [qrow][64-key chunk]
    __shared__ ushort Obuf[64 * 264];  // [qrow][256ch] (+pad) normalized O, bf16

    const int rb = (nd * 49 + p) * 4;
    int wid[4];
#pragma unroll
    for (int i = 0; i < 4; ++i) wid[i] = ridx[rb + i];

    const size_t kvband = (size_t)ndkv * 49;
    const size_t qrow0 = (size_t)(nd * 49 + p) * 64;

    const int pix = tid >> 2, ck = tid & 3;                 // K staging
    const int key_l = (tid & 31) * 2, ch0 = (tid >> 5) * 4; // V staging
    const int prow = (wv * 16 + lane15) * 72;

#pragma unroll 1
    for (int h = 0; h < 8; ++h) {
        __syncthreads();   // protect Ks/Vt against previous head's readers

        // ---- stage K: [key][32ch] bf16 ----
#pragma unroll
        for (int i = 0; i < 4; ++i) {
            size_t trow = (kvband + wid[i]) * 64 + pix;
            bf16x8 v = *(const bf16x8*)(kvbuf + trow * 512 + h * 32 + ck * 8);
            *(bf16x8*)&Ks[(i * 64 + pix) * 40 + ck * 8] = v;
        }
        // ---- stage V transposed: Vt[ch][key] ----
#pragma unroll
        for (int i = 0; i < 4; ++i) {
            size_t trow = (kvband + wid[i]) * 64;
            const ushort* g0 = kvbuf + (trow + key_l) * 512 + 256 + h * 32 + ch0;
            const ushort* g1 = g0 + 512;
            ushort4 a = *(const ushort4*)g0;
            ushort4 b = *(const ushort4*)g1;
            int kg = i * 64 + key_l;
            *(unsigned*)&Vt[(ch0 + 0) * 264 + kg] = (unsigned)a.x | ((unsigned)b.x << 16);
            *(unsigned*)&Vt[(ch0 + 1) * 264 + kg] = (unsigned)a.y | ((unsigned)b.y << 16);
            *(unsigned*)&Vt[(ch0 + 2) * 264 + kg] = (unsigned)a.z | ((unsigned)b.z << 16);
            *(unsigned*)&Vt[(ch0 + 3) * 264 + kg] = (unsigned)a.w | ((unsigned)b.w << 16);
        }

        // ---- Q B-frag from global (wave's own 16 q-rows) ----
        bf16x8 bQ = *(const bf16x8*)(qbuf + (qrow0 + wv * 16 + lane15) * 256 + h * 32 + quad * 8);

        __syncthreads();

        // ---- S^T = K · Q^T ----
        f32x4 st[16];
#pragma unroll
        for (int t = 0; t < 16; ++t) {
            bf16x8 aK = *(const bf16x8*)&Ks[(t * 16 + lane15) * 40 + quad * 8];
            st[t] = __builtin_amdgcn_mfma_f32_16x16x32_bf16(aK, bQ, (f32x4){0.f, 0.f, 0.f, 0.f}, 0, 0, 0);
        }

        // ---- softmax: bare exp2 (v_exp_f32), norm deferred to Obuf write ----
        float sum = 0.f;
#pragma unroll
        for (int t = 0; t < 16; ++t)
#pragma unroll
            for (int r = 0; r < 4; ++r) {
                float e = __builtin_amdgcn_exp2f(st[t][r]);
                st[t][r] = e;
                sum += e;
            }
        sum += __shfl_xor(sum, 16);
        sum += __shfl_xor(sum, 32);
        const float inv = 1.f / sum;

        // ---- PV in 4 key-chunks of 64, unnormalized P through LDS ----
        f32x4 oacc[2] = {{0.f, 0.f, 0.f, 0.f}, {0.f, 0.f, 0.f, 0.f}};
#pragma unroll
        for (int cc = 0; cc < 4; ++cc) {
#pragma unroll
            for (int tt = 0; tt < 4; ++tt) {
                int t = cc * 4 + tt;
                uint2 pk;
                pk.x = pk2bf(st[t][0], st[t][1]);
                pk.y = pk2bf(st[t][2], st[t][3]);
                *(uint2*)&Ps[prow + tt * 16 + quad * 4] = pk;
            }
#pragma unroll
            for (int kt = 0; kt < 2; ++kt) {
                bf16x8 aP = *(const bf16x8*)&Ps[prow + kt * 32 + quad * 8];
#pragma unroll
                for (int nt = 0; nt < 2; ++nt) {
                    bf16x8 bV = *(const bf16x8*)&Vt[(nt * 16 + lane15) * 264 + cc * 64 + kt * 32 + quad * 8];
                    oacc[nt] = __builtin_amdgcn_mfma_f32_16x16x32_bf16(aP, bV, oacc[nt], 0, 0, 0);
                }
            }
        }

        // ---- normalized O (bf16) into Obuf: rows quad*4+r, cols h*32+nt*16+l ----
#pragma unroll
        for (int nt = 0; nt < 2; ++nt)
#pragma unroll
            for (int r = 0; r < 4; ++r)
                Obuf[(wv * 16 + quad * 4 + r) * 264 + h * 32 + nt * 16 + lane15] =
                    f2bf(oacc[nt][r] * inv);
    }
    __syncthreads();   // Obuf complete

    // ---- output projection: out(64x256) = Obuf(64x256) @ Wo(256x256) + bo ----
    f32x4 acc[16];
#pragma unroll
    for (int nt = 0; nt < 16; ++nt) acc[nt] = (f32x4){0.f, 0.f, 0.f, 0.f};

#pragma unroll 1
    for (int kt = 0; kt < 8; ++kt) {
        bf16x8 aO = *(const bf16x8*)&Obuf[(wv * 16 + lane15) * 264 + kt * 32 + quad * 8];
#pragma unroll
        for (int nt = 0; nt < 16; ++nt) {
            bf16x8 bW = *(const bf16x8*)(Wot + (size_t)(nt * 16 + lane15) * 256 + kt * 32 + quad * 8);
            acc[nt] = __builtin_amdgcn_mfma_f32_16x16x32_bf16(aO, bW, acc[nt], 0, 0, 0);
        }
    }

    // ---- epilogue: bias + scatter to [nd][H][W][C] fp32 ----
    const int j = p / 7, i = p % 7;
#pragma unroll
    for (int nt = 0; nt < 16; ++nt) {
        int col = nt * 16 + lane15;
        float bias = bo[col];
#pragma unroll
        for (int r = 0; r < 4; ++r) {
            int row = wv * 16 + quad * 4 + r;
            int hh = row >> 3, ww = row & 7;
            int xr = nd * 3136 + (j * 8 + hh) * 56 + (i * 8 + ww);
            out[(size_t)xr * 256 + col] = acc[nt][r] + bias;
        }
    }
}

// ---------------------------------------------------------------------------
extern "C" void kernel_launch(void* const* d_in, const int* in_sizes, int n_in,
                              void* d_out, int out_size, void* d_ws, size_t ws_size,
                              hipStream_t stream) {
    const float* x    = (const float*)d_in[0];
    const float* Wqkv = (const float*)d_in[1];
    const float* bqkv = (const float*)d_in[2];
    const float* Wo   = (const float*)d_in[3];
    const float* bo   = (const float*)d_in[4];
    float* out = (float*)d_out;

    char* ws = (char*)d_ws;
    ushort* xg    = (ushort*)ws;                    ws += (size_t)50176 * 256 * 2;
    ushort* q     = (ushort*)ws;                    ws += (size_t)50176 * 256 * 2;
    ushort* kv    = (ushort*)ws;                    ws += (size_t)50176 * 512 * 2;
    ushort* Wqkvt = (ushort*)ws;                    ws += (size_t)768 * 256 * 2;
    ushort* Wot   = (ushort*)ws;                    ws += (size_t)256 * 256 * 2;
    float*  xmean = (float*)ws;                     ws += (size_t)784 * 256 * 4;
    float*  qwin  = (float*)ws;                     ws += (size_t)784 * 256 * 4;
    float*  kwin  = (float*)ws;                     ws += (size_t)784 * 256 * 4;
    int*    ridx  = (int*)ws;

    k_cast_w  <<<1024, 256, 0, stream>>>(Wqkv, Wo, Wqkvt, Wot);
    k_prep    <<<784, 256, 0, stream>>>(x, xg, xmean);
    k_winproj <<<dim3(8, 13), 256, 0, stream>>>(xmean, Wqkv, bqkv, qwin, kwin);
    k_route   <<<784, 64, 0, stream>>>(qwin, kwin, ridx);
    k_gemm_qkv<<<dim3(6, 392), 256, 0, stream>>>(xg, Wqkvt, bqkv, q, kv);
    k_attn_o  <<<dim3(49, 16), 256, 0, stream>>>(q, kv, Wot, ridx, bo, out);
}

// Round 6
// 253.425 us; speedup vs baseline: 1.2592x; 1.2592x over previous
//
#include <hip/hip_runtime.h>
#include <hip/hip_bf16.h>
#include <math.h>

// attention scale folded with log2(e) for exp2-based softmax:
// q_attn = q * (256^-0.5 * log2(e))
#define QSC 0.09016844f

typedef __attribute__((ext_vector_type(8))) short bf16x8;
typedef __attribute__((ext_vector_type(4))) float f32x4;

// fp32 -> bf16 round-to-nearest-even
__device__ __forceinline__ ushort f2bf(float f) {
    unsigned u = __float_as_uint(f);
    return (ushort)((u + 0x7FFFu + ((u >> 16) & 1u)) >> 16);
}

__device__ __forceinline__ unsigned pk2bf(float a, float b) {
    __hip_bfloat162 h = __float22bfloat162_rn(make_float2(a, b));
    return *(unsigned*)&h;
}

// async global->LDS, 16B per lane. LDS dest must be wave-uniform base + lane*16.
__device__ __forceinline__ void gl_lds16(const ushort* g, ushort* l) {
    __builtin_amdgcn_global_load_lds(
        (const __attribute__((address_space(1))) unsigned int*)g,
        (__attribute__((address_space(3))) unsigned int*)l, 16, 0, 0);
}

// XOR swizzle for DMA-staged [row][4x8ushort] tiles: kills the 8-way
// fragment-read conflict (row stride 64B) without padding.
__device__ __forceinline__ int swz(int row) { return (row ^ (row >> 2)) & 3; }

// token t (window order: [nd][p][pix]) -> row in x/out layout [nd][H][W]
__device__ __forceinline__ int token_to_xrow(int t) {
    int nd  = t / 3136;          // 49*64
    int r   = t % 3136;
    int p   = r >> 6;            // window 0..48
    int pix = r & 63;            // pixel 0..63
    int j = p / 7, i = p % 7;
    int hh = pix >> 3, ww = pix & 7;
    return nd * 3136 + (j * 8 + hh) * 56 + (i * 8 + ww);
}

// ---------------------------------------------------------------------------
// K1: merged prep. Blocks [0,784): window-gather cast x->xg (bf16, window
// order) + fp32 window means (one pass over x). Blocks [784,1808): weight
// transpose+cast.
// ---------------------------------------------------------------------------
__global__ __launch_bounds__(256) void k_prep(const float* __restrict__ x,
                                              const float* __restrict__ Wqkv,
                                              const float* __restrict__ Wo,
                                              ushort* __restrict__ xg,
                                              float* __restrict__ xmean,
                                              ushort* __restrict__ Wqkvt,
                                              ushort* __restrict__ Wot) {
    int b = blockIdx.x;
    int tid = threadIdx.x;
    if (b >= 784) {
        int bb = b - 784;
        if (bb < 768) Wqkvt[bb * 256 + tid] = f2bf(Wqkv[(size_t)tid * 768 + bb]);
        else { int n = bb - 768; Wot[n * 256 + tid] = f2bf(Wo[(size_t)tid * 256 + n]); }
        return;
    }
    int nd = b / 49, p = b % 49;
    int j = p / 7, i = p % 7;
    const float* xb = x + ((size_t)nd * 3136 + (j * 8) * 56 + i * 8) * 256 + tid;
    ushort* xo = xg + (size_t)b * 64 * 256 + tid;
    float s = 0.f;
#pragma unroll 2
    for (int hh = 0; hh < 8; ++hh)
#pragma unroll
        for (int ww = 0; ww < 8; ++ww) {
            float v = xb[(size_t)(hh * 56 + ww) * 256];
            s += v;
            xo[(size_t)(hh * 8 + ww) * 256] = f2bf(v);
        }
    xmean[(size_t)b * 256 + tid] = s * (1.f / 64.f);
}

// ---------------------------------------------------------------------------
// Routing projection, pure fp32 (decoupled from bf16 numerics).
// ---------------------------------------------------------------------------
__global__ __launch_bounds__(256) void k_winproj(const float* __restrict__ xmean,
                                                 const float* __restrict__ Wqkv,
                                                 const float* __restrict__ bqkv,
                                                 float* __restrict__ qwin,
                                                 float* __restrict__ kwin) {
    __shared__ float As[16 * 68];
    __shared__ float Bs[16 * 64];
    const int tid = threadIdx.x;
    const int m0 = blockIdx.y * 64;
    const int n0 = blockIdx.x * 64;

    const int ar = tid >> 2;
    const int ak = (tid & 3) * 4;
    const int arow = (m0 + ar < 784) ? (m0 + ar) : 783;
    const float* aptr = xmean + (size_t)arow * 256 + ak;

    const int bk = tid >> 4;
    const int bn = (tid & 15) * 4;
    const float* bptr = Wqkv + (size_t)bk * 768 + n0 + bn;

    const int ty = tid >> 4, tx = tid & 15;
    float acc[4][4] = {};

    for (int kt = 0; kt < 256; kt += 16) {
        float4 av = *(const float4*)(aptr + kt);
        float4 bv = *(const float4*)(bptr + (size_t)kt * 768);
        __syncthreads();
        As[(ak + 0) * 68 + ar] = av.x;
        As[(ak + 1) * 68 + ar] = av.y;
        As[(ak + 2) * 68 + ar] = av.z;
        As[(ak + 3) * 68 + ar] = av.w;
        *(float4*)&Bs[bk * 64 + bn] = bv;
        __syncthreads();
#pragma unroll
        for (int kk = 0; kk < 16; ++kk) {
            float4 a4 = *(const float4*)&As[kk * 68 + ty * 4];
            float4 b4 = *(const float4*)&Bs[kk * 64 + tx * 4];
            float a[4] = {a4.x, a4.y, a4.z, a4.w};
            float b[4] = {b4.x, b4.y, b4.z, b4.w};
#pragma unroll
            for (int ii = 0; ii < 4; ++ii)
#pragma unroll
                for (int jj = 0; jj < 4; ++jj) acc[ii][jj] += a[ii] * b[jj];
        }
    }
#pragma unroll
    for (int ii = 0; ii < 4; ++ii) {
        int t = m0 + ty * 4 + ii;
        if (t >= 784) continue;
#pragma unroll
        for (int jj = 0; jj < 4; ++jj) {
            int col = n0 + tx * 4 + jj;
            float v = acc[ii][jj] + bqkv[col];
            if (col < 256) qwin[(size_t)t * 256 + col] = v;
            else           kwin[(size_t)t * 256 + (col - 256)] = v;
        }
    }
}

__global__ __launch_bounds__(64) void k_route(const float* __restrict__ qwin,
                                              const float* __restrict__ kwin,
                                              int* __restrict__ ridx) {
    const int b = blockIdx.x;                 // nd*49 + p
    const int nd = b / 49;
    const int ndkv = ((nd & 7) == 7) ? nd : nd + 1;
    const int t = threadIdx.x;
    __shared__ float qs[256];
    for (int i = t; i < 256; i += 64) qs[i] = qwin[b * 256 + i];
    __syncthreads();
    float logit = -INFINITY;
    if (t < 49) {
        const float* kr = kwin + ((size_t)ndkv * 49 + t) * 256;
        float s = 0.f;
        for (int c = 0; c < 256; ++c) s += qs[c] * kr[c];
        logit = s;
    }
    for (int sel = 0; sel < 4; ++sel) {
        float v = logit;
        int ix = t;
        for (int off = 32; off > 0; off >>= 1) {
            float ov = __shfl_xor(v, off);
            int   oi = __shfl_xor(ix, off);
            if (ov > v || (ov == v && oi < ix)) { v = ov; ix = oi; }
        }
        if (t == 0) ridx[b * 4 + sel] = ix;
        if (t == ix) logit = -INFINITY;
    }
}

// ---------------------------------------------------------------------------
// K2: bf16 MFMA GEMM, 128x128 tile, BK=32, direct-to-LDS staging with XOR
// swizzle (fragment reads 2-way bank aliased = free). q gets folded scale.
// ---------------------------------------------------------------------------
__global__ __launch_bounds__(256) void k_gemm_qkv(const ushort* __restrict__ A,
                                                  const ushort* __restrict__ Bt,
                                                  const float* __restrict__ bqkv,
                                                  ushort* __restrict__ q,
                                                  ushort* __restrict__ kv) {
    __shared__ ushort As[128 * 32];
    __shared__ ushort Bs[128 * 32];
    const int tid = threadIdx.x;
    const int wv = tid >> 6, ln = tid & 63;
    const int lane15 = ln & 15, quad = ln >> 4;
    const int m0 = blockIdx.y * 128, n0 = blockIdx.x * 128;
    const int row0 = tid >> 2, ck0 = tid & 3;

    const ushort* gA[2]; const ushort* gB[2];
    ushort* lA[2]; ushort* lB[2];
#pragma unroll
    for (int p = 0; p < 2; ++p) {
        int r = p * 64 + row0;
        int cks = ck0 ^ swz(r);               // swizzled chunk this lane stages
        gA[p] = A  + (size_t)(m0 + r) * 256 + cks * 8;
        gB[p] = Bt + (size_t)(n0 + r) * 256 + cks * 8;
        lA[p] = &As[(p * 256 + tid) * 8];
        lB[p] = &Bs[(p * 256 + tid) * 8];
    }

    f32x4 acc[4][4];
#pragma unroll
    for (int i = 0; i < 4; ++i)
#pragma unroll
        for (int j = 0; j < 4; ++j) acc[i][j] = (f32x4){0.f, 0.f, 0.f, 0.f};

    const int mb = (wv >> 1) * 64, nb = (wv & 1) * 64;

    for (int kt = 0; kt < 8; ++kt) {
        __syncthreads();
#pragma unroll
        for (int p = 0; p < 2; ++p) {
            gl_lds16(gA[p] + kt * 32, lA[p]);
            gl_lds16(gB[p] + kt * 32, lB[p]);
        }
        __syncthreads();
        bf16x8 aF[4], bF[4];
#pragma unroll
        for (int mt = 0; mt < 4; ++mt) {
            int r = mb + mt * 16 + lane15;
            aF[mt] = *(const bf16x8*)&As[r * 32 + (quad ^ swz(r)) * 8];
        }
#pragma unroll
        for (int nt = 0; nt < 4; ++nt) {
            int r = nb + nt * 16 + lane15;
            bF[nt] = *(const bf16x8*)&Bs[r * 32 + (quad ^ swz(r)) * 8];
        }
#pragma unroll
        for (int mt = 0; mt < 4; ++mt)
#pragma unroll
            for (int nt = 0; nt < 4; ++nt)
                acc[mt][nt] = __builtin_amdgcn_mfma_f32_16x16x32_bf16(aF[mt], bF[nt], acc[mt][nt], 0, 0, 0);
    }

#pragma unroll
    for (int mt = 0; mt < 4; ++mt) {
#pragma unroll
        for (int nt = 0; nt < 4; ++nt) {
            int col = n0 + nb + nt * 16 + lane15;
            float bias = bqkv[col];
#pragma unroll
            for (int r = 0; r < 4; ++r) {
                int t = m0 + mb + mt * 16 + quad * 4 + r;
                float v = acc[mt][nt][r] + bias;
                if (col < 256) q[(size_t)t * 256 + col] = f2bf(v * QSC);
                else           kv[(size_t)t * 512 + (col - 256)] = f2bf(v);
            }
        }
    }
}

// ---------------------------------------------------------------------------
// K4: output projection GEMM (swizzled staging) + un-window scatter, fp32 out.
// ---------------------------------------------------------------------------
__global__ __launch_bounds__(256) void k_gemm_o(const ushort* __restrict__ A,
                                                const ushort* __restrict__ Bt,
                                                const float* __restrict__ bo,
                                                float* __restrict__ out) {
    __shared__ ushort As[128 * 32];
    __shared__ ushort Bs[128 * 32];
    const int tid = threadIdx.x;
    const int wv = tid >> 6, ln = tid & 63;
    const int lane15 = ln & 15, quad = ln >> 4;
    const int m0 = blockIdx.y * 128, n0 = blockIdx.x * 128;
    const int row0 = tid >> 2, ck0 = tid & 3;

    const ushort* gA[2]; const ushort* gB[2];
    ushort* lA[2]; ushort* lB[2];
#pragma unroll
    for (int p = 0; p < 2; ++p) {
        int r = p * 64 + row0;
        int cks = ck0 ^ swz(r);
        gA[p] = A  + (size_t)(m0 + r) * 256 + cks * 8;
        gB[p] = Bt + (size_t)(n0 + r) * 256 + cks * 8;
        lA[p] = &As[(p * 256 + tid) * 8];
        lB[p] = &Bs[(p * 256 + tid) * 8];
    }

    f32x4 acc[4][4];
#pragma unroll
    for (int i = 0; i < 4; ++i)
#pragma unroll
        for (int j = 0; j < 4; ++j) acc[i][j] = (f32x4){0.f, 0.f, 0.f, 0.f};

    const int mb = (wv >> 1) * 64, nb = (wv & 1) * 64;

    for (int kt = 0; kt < 8; ++kt) {
        __syncthreads();
#pragma unroll
        for (int p = 0; p < 2; ++p) {
            gl_lds16(gA[p] + kt * 32, lA[p]);
            gl_lds16(gB[p] + kt * 32, lB[p]);
        }
        __syncthreads();
        bf16x8 aF[4], bF[4];
#pragma unroll
        for (int mt = 0; mt < 4; ++mt) {
            int r = mb + mt * 16 + lane15;
            aF[mt] = *(const bf16x8*)&As[r * 32 + (quad ^ swz(r)) * 8];
        }
#pragma unroll
        for (int nt = 0; nt < 4; ++nt) {
            int r = nb + nt * 16 + lane15;
            bF[nt] = *(const bf16x8*)&Bs[r * 32 + (quad ^ swz(r)) * 8];
        }
#pragma unroll
        for (int mt = 0; mt < 4; ++mt)
#pragma unroll
            for (int nt = 0; nt < 4; ++nt)
                acc[mt][nt] = __builtin_amdgcn_mfma_f32_16x16x32_bf16(aF[mt], bF[nt], acc[mt][nt], 0, 0, 0);
    }

#pragma unroll
    for (int mt = 0; mt < 4; ++mt) {
#pragma unroll
        for (int nt = 0; nt < 4; ++nt) {
            int col = n0 + nb + nt * 16 + lane15;
            float bias = bo[col];
#pragma unroll
            for (int r = 0; r < 4; ++r) {
                int t = m0 + mb + mt * 16 + quad * 4 + r;
                int xr = token_to_xrow(t);
                out[(size_t)xr * 256 + col] = acc[mt][nt][r] + bias;
            }
        }
    }
}

// ---------------------------------------------------------------------------
// K3: attention per (head, window, nd). q already carries SCALE*log2e:
// softmax = exp2(score), normalization deferred to the output store.
// LDS strides: Ks 40 (2-way banks), Vt 264 (2-way), Ps 72 (2-way).
// 6272 blocks, ~46.6 KB LDS -> 3 blocks/CU.
// ---------------------------------------------------------------------------
__global__ __launch_bounds__(256, 3) void k_attn(ushort* qbuf,
                                                 const ushort* __restrict__ kvbuf,
                                                 const int* __restrict__ ridx) {
    const int h = blockIdx.x, p = blockIdx.y, nd = blockIdx.z;
    const int ndkv = ((nd & 7) == 7) ? nd : nd + 1;
    const int tid = threadIdx.x;
    const int wv = tid >> 6, ln = tid & 63;
    const int lane15 = ln & 15, quad = ln >> 4;

    __shared__ ushort Ks[256 * 40];   // [key][ch] stride 40: 20 KB
    __shared__ ushort Vt[32 * 264];   // [ch][key] stride 264: 16.5 KB
    __shared__ ushort Ps[64 * 72];    // [qrow][64key chunk]: 9 KB

    const int rb = (nd * 49 + p) * 4;
    int wid[4];
#pragma unroll
    for (int i = 0; i < 4; ++i) wid[i] = ridx[rb + i];

    const size_t kvband = (size_t)ndkv * 49;

    // ---- stage K: [key][32ch] bf16 ----
    {
        int pix = tid >> 2, ck = tid & 3;
#pragma unroll
        for (int i = 0; i < 4; ++i) {
            size_t trow = (kvband + wid[i]) * 64 + pix;
            bf16x8 v = *(const bf16x8*)(kvbuf + trow * 512 + h * 32 + ck * 8);
            *(bf16x8*)&Ks[(i * 64 + pix) * 40 + ck * 8] = v;
        }
    }
    // ---- stage V transposed: Vt[ch][key] ----
    {
        int key_l = (tid & 31) * 2;       // 0..62 within window
        int ch0 = (tid >> 5) * 4;         // 0..28
#pragma unroll
        for (int i = 0; i < 4; ++i) {
            size_t trow = (kvband + wid[i]) * 64;
            const ushort* g0 = kvbuf + (trow + key_l) * 512 + 256 + h * 32 + ch0;
            const ushort* g1 = g0 + 512;
            ushort4 a = *(const ushort4*)g0;
            ushort4 b = *(const ushort4*)g1;
            int kg = i * 64 + key_l;
            *(unsigned*)&Vt[(ch0 + 0) * 264 + kg] = (unsigned)a.x | ((unsigned)b.x << 16);
            *(unsigned*)&Vt[(ch0 + 1) * 264 + kg] = (unsigned)a.y | ((unsigned)b.y << 16);
            *(unsigned*)&Vt[(ch0 + 2) * 264 + kg] = (unsigned)a.z | ((unsigned)b.z << 16);
            *(unsigned*)&Vt[(ch0 + 3) * 264 + kg] = (unsigned)a.w | ((unsigned)b.w << 16);
        }
    }

    // ---- Q B-frag from global (wave's own 16 q-rows) ----
    const size_t qrow0 = (size_t)(nd * 49 + p) * 64;
    bf16x8 bQ = *(const bf16x8*)(qbuf + (qrow0 + wv * 16 + lane15) * 256 + h * 32 + quad * 8);

    __syncthreads();

    // ---- S^T = K · Q^T ----
    f32x4 st[16];
#pragma unroll
    for (int t = 0; t < 16; ++t) {
        bf16x8 aK = *(const bf16x8*)&Ks[(t * 16 + lane15) * 40 + quad * 8];
        st[t] = __builtin_amdgcn_mfma_f32_16x16x32_bf16(aK, bQ, (f32x4){0.f, 0.f, 0.f, 0.f}, 0, 0, 0);
    }

    // ---- softmax: bare exp2 (v_exp_f32), no max, norm deferred ----
    float sum = 0.f;
#pragma unroll
    for (int t = 0; t < 16; ++t)
#pragma unroll
        for (int r = 0; r < 4; ++r) {
            float e = __builtin_amdgcn_exp2f(st[t][r]);
            st[t][r] = e;
            sum += e;
        }
    sum += __shfl_xor(sum, 16);
    sum += __shfl_xor(sum, 32);
    const float inv = 1.f / sum;

    // ---- PV in 4 key-chunks of 64, unnormalized P through LDS ----
    f32x4 oacc[2] = {{0.f, 0.f, 0.f, 0.f}, {0.f, 0.f, 0.f, 0.f}};
    const int prow = (wv * 16 + lane15) * 72;
#pragma unroll
    for (int cc = 0; cc < 4; ++cc) {
#pragma unroll
        for (int tt = 0; tt < 4; ++tt) {
            int t = cc * 4 + tt;
            uint2 pk;
            pk.x = pk2bf(st[t][0], st[t][1]);
            pk.y = pk2bf(st[t][2], st[t][3]);
            *(uint2*)&Ps[prow + tt * 16 + quad * 4] = pk;
        }
#pragma unroll
        for (int kt = 0; kt < 2; ++kt) {
            bf16x8 aP = *(const bf16x8*)&Ps[prow + kt * 32 + quad * 8];
#pragma unroll
            for (int nt = 0; nt < 2; ++nt) {
                bf16x8 bV = *(const bf16x8*)&Vt[(nt * 16 + lane15) * 264 + cc * 64 + kt * 32 + quad * 8];
                oacc[nt] = __builtin_amdgcn_mfma_f32_16x16x32_bf16(aP, bV, oacc[nt], 0, 0, 0);
            }
        }
    }

    // ---- store (in-place over qbuf; wave owns exactly its 16 rows) ----
#pragma unroll
    for (int nt = 0; nt < 2; ++nt)
#pragma unroll
        for (int r = 0; r < 4; ++r) {
            int row = wv * 16 + quad * 4 + r;
            qbuf[(qrow0 + row) * 256 + h * 32 + nt * 16 + lane15] = f2bf(oacc[nt][r] * inv);
        }
}

// ---------------------------------------------------------------------------
extern "C" void kernel_launch(void* const* d_in, const int* in_sizes, int n_in,
                              void* d_out, int out_size, void* d_ws, size_t ws_size,
                              hipStream_t stream) {
    const float* x    = (const float*)d_in[0];
    const float* Wqkv = (const float*)d_in[1];
    const float* bqkv = (const float*)d_in[2];
    const float* Wo   = (const float*)d_in[3];
    const float* bo   = (const float*)d_in[4];
    float* out = (float*)d_out;

    char* ws = (char*)d_ws;
    ushort* xg    = (ushort*)ws;                    ws += (size_t)50176 * 256 * 2;
    ushort* q     = (ushort*)ws;                    ws += (size_t)50176 * 256 * 2;
    ushort* kv    = (ushort*)ws;                    ws += (size_t)50176 * 512 * 2;
    ushort* Wqkvt = (ushort*)ws;                    ws += (size_t)768 * 256 * 2;
    ushort* Wot   = (ushort*)ws;                    ws += (size_t)256 * 256 * 2;
    float*  xmean = (float*)ws;                     ws += (size_t)784 * 256 * 4;
    float*  qwin  = (float*)ws;                     ws += (size_t)784 * 256 * 4;
    float*  kwin  = (float*)ws;                     ws += (size_t)784 * 256 * 4;
    int*    ridx  = (int*)ws;

    k_prep    <<<1808, 256, 0, stream>>>(x, Wqkv, Wo, xg, xmean, Wqkvt, Wot);
    k_winproj <<<dim3(8, 13), 256, 0, stream>>>(xmean, Wqkv, bqkv, qwin, kwin);
    k_route   <<<784, 64, 0, stream>>>(qwin, kwin, ridx);
    k_gemm_qkv<<<dim3(6, 392), 256, 0, stream>>>(xg, Wqkvt, bqkv, q, kv);
    k_attn    <<<dim3(8, 49, 16), 256, 0, stream>>>(q, kv, ridx);
    k_gemm_o  <<<dim3(2, 392), 256, 0, stream>>>(q, Wot, bo, out);
}